// Round 1
// baseline (204.905 us; speedup 1.0000x reference)
//
#include <hip/hip_runtime.h>
#include <math.h>

// Shapes: B=32 T=64 N=16 A=20 D=128 S=32 E=64 H=256; batch=2048
// coal:  coal[b,i,a] = (1/512) * sum_s q[s][i] * #{ j < q[s][i] : a_idx(q[s][j])==a }
// w1  :  |relu(st@W1a+b1a) @ W1b + b1b|  (per batch, 40x64)
// out :  q_tot (2048) ++ w_est (2048*16)

#define BATCH 2048

// ---------------- Kernel A: per-batch small MLPs, 8 batches/block ----------------
__global__ __launch_bounds__(256) void kA(
    const float* __restrict__ states,
    const float* __restrict__ W1a, const float* __restrict__ b1a,
    const float* __restrict__ Wb,  const float* __restrict__ bb,
    const float* __restrict__ Wfa, const float* __restrict__ bfa,
    const float* __restrict__ Wfb, const float* __restrict__ bfb,
    const float* __restrict__ Wv1, const float* __restrict__ bv1,
    const float* __restrict__ Wv2, const float* __restrict__ bv2,
    float* __restrict__ h1, float* __restrict__ b1buf,
    float* __restrict__ wfbuf, float* __restrict__ vbuf)
{
    __shared__ float st8[8][128];
    __shared__ float hf8[8][256];
    __shared__ float vpart[8][64];
    __shared__ float wfpart[2][8][64];
    const int t = threadIdx.x;
    const int b0 = blockIdx.x * 8;

    { // load 8 batches of states (1024 floats = 256 float4)
        int g = t >> 5, d4 = (t & 31) << 2;
        float4 v = *(const float4*)&states[(b0 + g) * 128 + d4];
        st8[g][d4] = v.x; st8[g][d4+1] = v.y; st8[g][d4+2] = v.z; st8[g][d4+3] = v.w;
    }
    __syncthreads();

    { // h1 and hf: each thread owns one hidden unit h=t for all 8 batches
        const int h = t;
        float acc1[8] = {0,0,0,0,0,0,0,0}, accf[8] = {0,0,0,0,0,0,0,0};
        for (int d = 0; d < 128; ++d) {
            float wa = W1a[d * 256 + h];
            float wf2 = Wfa[d * 256 + h];
            #pragma unroll
            for (int g = 0; g < 8; ++g) {
                float s = st8[g][d];
                acc1[g] = fmaf(s, wa, acc1[g]);
                accf[g] = fmaf(s, wf2, accf[g]);
            }
        }
        float ba = b1a[h], bf = bfa[h];
        #pragma unroll
        for (int g = 0; g < 8; ++g) {
            h1[(b0 + g) * 256 + h] = fmaxf(acc1[g] + ba, 0.f);
            hf8[g][h] = fmaxf(accf[g] + bf, 0.f);
        }
    }
    __syncthreads();

    const int e = t & 63, role = t >> 6;
    if (role == 0) {            // b1 = st@Wb + bb
        float acc[8] = {0,0,0,0,0,0,0,0};
        for (int d = 0; d < 128; ++d) {
            float w = Wb[d * 64 + e];
            #pragma unroll
            for (int g = 0; g < 8; ++g) acc[g] = fmaf(st8[g][d], w, acc[g]);
        }
        float bbv = bb[e];
        #pragma unroll
        for (int g = 0; g < 8; ++g) b1buf[(b0 + g) * 64 + e] = acc[g] + bbv;
    } else if (role == 1) {     // v partials: relu(st@Wv1+bv1)*Wv2
        float acc[8] = {0,0,0,0,0,0,0,0};
        for (int d = 0; d < 128; ++d) {
            float w = Wv1[d * 64 + e];
            #pragma unroll
            for (int g = 0; g < 8; ++g) acc[g] = fmaf(st8[g][d], w, acc[g]);
        }
        float w2 = Wv2[e], bv = bv1[e];
        #pragma unroll
        for (int g = 0; g < 8; ++g) vpart[g][e] = fmaxf(acc[g] + bv, 0.f) * w2;
    } else {                    // w_final partials: hf@Wfb split over h halves
        const int half = role - 2;
        float acc[8] = {0,0,0,0,0,0,0,0};
        for (int h2 = half * 128; h2 < half * 128 + 128; ++h2) {
            float w = Wfb[h2 * 64 + e];
            #pragma unroll
            for (int g = 0; g < 8; ++g) acc[g] = fmaf(hf8[g][h2], w, acc[g]);
        }
        #pragma unroll
        for (int g = 0; g < 8; ++g) wfpart[half][g][e] = acc[g];
    }
    __syncthreads();

    { // combine w_final halves (each thread handles g and g+4)
        int g = t >> 6;
        float bf = bfb[e];
        wfbuf[(b0 + g) * 64 + e]     = fabsf(wfpart[0][g][e]     + wfpart[1][g][e]     + bf);
        wfbuf[(b0 + g + 4) * 64 + e] = fabsf(wfpart[0][g + 4][e] + wfpart[1][g + 4][e] + bf);
    }
    if (t < 8) { // v reduce over e
        float s = 0.f;
        for (int e2 = 0; e2 < 64; ++e2) s += vpart[t][e2];
        vbuf[b0 + t] = s + bv2[0];
    }
}

// ---------------- Kernel B: coalition term via permutation bitmasks ----------------
__global__ __launch_bounds__(320) void kB(
    const float* __restrict__ actions, const int* __restrict__ gc,
    float* __restrict__ coal)
{
    __shared__ int aidx[16];
    __shared__ int q[32][16];
    __shared__ unsigned int msk[32][20];
    const int t = threadIdx.x;
    const int b = blockIdx.x;

    for (int idx = t; idx < 512; idx += 320) ((int*)q)[idx] = gc[b * 512 + idx];
    if (t < 16) {
        int a = 0;
        const float* ap = &actions[(b * 16 + t) * 20];
        for (int k = 0; k < 20; ++k) if (ap[k] > 0.5f) a = k;
        aidx[t] = a;
    }
    for (int idx = t; idx < 640; idx += 320) ((unsigned int*)msk)[idx] = 0u;
    __syncthreads();

    if (t < 32) { // one thread per sample s: build per-action position masks
        #pragma unroll
        for (int j = 0; j < 16; ++j) {
            int a = aidx[q[t][j]];
            msk[t][a] |= (1u << j);
        }
    }
    __syncthreads();

    // thread t -> (i = t/20, a = t%20)
    const int i = t / 20, a = t % 20;
    float acc = 0.f;
    #pragma unroll 8
    for (int s = 0; s < 32; ++s) {
        int g = q[s][i];
        acc += (float)(g * __popc(msk[s][a] & ((1u << g) - 1u)));
    }
    coal[b * 320 + t] = acc * (1.0f / 512.0f);
}

// ---------------- Kernel C: w1 = |h1 @ W1b + b1b|, M=2048 K=256 N=2560 ----------------
__global__ __launch_bounds__(256) void kC(
    const float* __restrict__ A,    // h1: 2048 x 256
    const float* __restrict__ Bw,   // W1b: 256 x 2560
    const float* __restrict__ bias, // b1b: 2560
    float* __restrict__ C)          // w1: 2048 x 2560
{
    __shared__ float As[16][64];
    __shared__ float Bs[16][64];
    const int tid = threadIdx.x;
    const int tx = tid & 15, ty = tid >> 4;
    const int m0 = blockIdx.y * 64, n0 = blockIdx.x * 64;
    const int lm = tid >> 2;           // 0..63 (A row in tile)
    const int lk = (tid & 3) << 2;     // 0,4,8,12
    const int lkk = tid >> 4;          // 0..15 (B row in tile)
    const int lnb = (tid & 15) << 2;   // 0..60

    float c[4][4] = {{0}};
    for (int k0 = 0; k0 < 256; k0 += 16) {
        float4 av = *(const float4*)&A[(m0 + lm) * 256 + k0 + lk];
        As[lk][lm] = av.x; As[lk+1][lm] = av.y; As[lk+2][lm] = av.z; As[lk+3][lm] = av.w;
        float4 bv = *(const float4*)&Bw[(k0 + lkk) * 2560 + n0 + lnb];
        *(float4*)&Bs[lkk][lnb] = bv;
        __syncthreads();
        #pragma unroll
        for (int kk = 0; kk < 16; ++kk) {
            float4 a4 = *(const float4*)&As[kk][ty * 4];
            float4 b4 = *(const float4*)&Bs[kk][tx * 4];
            float aa[4] = {a4.x, a4.y, a4.z, a4.w};
            float bb4[4] = {b4.x, b4.y, b4.z, b4.w};
            #pragma unroll
            for (int i = 0; i < 4; ++i)
                #pragma unroll
                for (int j = 0; j < 4; ++j)
                    c[i][j] = fmaf(aa[i], bb4[j], c[i][j]);
        }
        __syncthreads();
    }
    const int n = n0 + tx * 4;
    float bx = bias[n], by = bias[n+1], bz = bias[n+2], bw = bias[n+3];
    #pragma unroll
    for (int i = 0; i < 4; ++i) {
        int m = m0 + ty * 4 + i;
        float4 o;
        o.x = fabsf(c[i][0] + bx);
        o.y = fabsf(c[i][1] + by);
        o.z = fabsf(c[i][2] + bz);
        o.w = fabsf(c[i][3] + bw);
        *(float4*)&C[m * 2560 + n] = o;
    }
}

// ---------------- Kernel D: hidden/elu, y, w_est, q_tot ----------------
__global__ __launch_bounds__(1024) void kD(
    const float* __restrict__ coal, const float* __restrict__ actions,
    const float* __restrict__ w1, const float* __restrict__ b1buf,
    const float* __restrict__ wfbuf, const float* __restrict__ vbuf,
    const float* __restrict__ agent_qs, float* __restrict__ out)
{
    __shared__ float ins[16][40];
    __shared__ float w1s[2560];
    __shared__ float wq[16];
    const int t = threadIdx.x, b = blockIdx.x;

    for (int idx = t; idx < 2560; idx += 1024) w1s[idx] = w1[b * 2560 + idx];
    if (t < 320) ins[t / 20][t % 20] = coal[b * 320 + t];
    else if (t < 640) { int u = t - 320; ins[u / 20][20 + u % 20] = actions[b * 320 + u]; }
    __syncthreads();

    const int i = t >> 6, e = t & 63; // wave i handles agent i, lane = e
    float acc = b1buf[b * 64 + e];
    #pragma unroll
    for (int k = 0; k < 40; ++k)
        acc = fmaf(ins[i][k], w1s[k * 64 + e], acc);
    float hidden = acc > 0.f ? acc : expm1f(acc);
    float p = hidden * wfbuf[b * 64 + e];
    #pragma unroll
    for (int off = 32; off > 0; off >>= 1)
        p += __shfl_down(p, off, 64);
    if (e == 0) {
        float west = fabsf(p + vbuf[b]);
        out[2048 + b * 16 + i] = west;
        wq[i] = west * agent_qs[b * 16 + i];
    }
    __syncthreads();
    if (t == 0) {
        float s = 0.f;
        #pragma unroll
        for (int ii = 0; ii < 16; ++ii) s += wq[ii];
        out[b] = s;
    }
}

extern "C" void kernel_launch(void* const* d_in, const int* in_sizes, int n_in,
                              void* d_out, int out_size, void* d_ws, size_t ws_size,
                              hipStream_t stream) {
    const float* states   = (const float*)d_in[0];
    const float* actions  = (const float*)d_in[1];
    const float* agent_qs = (const float*)d_in[2];
    // d_in[3] = max_filter (unused by reference)
    const int*   gc       = (const int*)d_in[4];
    const float* W1a = (const float*)d_in[5];
    const float* b1a = (const float*)d_in[6];
    const float* W1b = (const float*)d_in[7];
    const float* b1b = (const float*)d_in[8];
    const float* Wb  = (const float*)d_in[9];
    const float* bb  = (const float*)d_in[10];
    const float* Wfa = (const float*)d_in[11];
    const float* bfa = (const float*)d_in[12];
    const float* Wfb = (const float*)d_in[13];
    const float* bfb = (const float*)d_in[14];
    const float* Wv1 = (const float*)d_in[15];
    const float* bv1 = (const float*)d_in[16];
    const float* Wv2 = (const float*)d_in[17];
    const float* bv2 = (const float*)d_in[18];

    float* ws    = (float*)d_ws;
    float* h1    = ws;                 // 2048*256  = 524288
    float* coal  = h1 + 524288;        // 2048*320  = 655360
    float* b1buf = coal + 655360;      // 2048*64   = 131072
    float* wfbuf = b1buf + 131072;     // 2048*64   = 131072
    float* vbuf  = wfbuf + 131072;     // 2048
    float* w1    = vbuf + 2048;        // 2048*2560 = 5242880  (total ~26.8 MB)
    float* out   = (float*)d_out;

    kA<<<BATCH / 8, 256, 0, stream>>>(states, W1a, b1a, Wb, bb, Wfa, bfa,
                                      Wfb, bfb, Wv1, bv1, Wv2, bv2,
                                      h1, b1buf, wfbuf, vbuf);
    kB<<<BATCH, 320, 0, stream>>>(actions, gc, coal);
    kC<<<dim3(2560 / 64, 2048 / 64), 256, 0, stream>>>(h1, W1b, b1b, w1);
    kD<<<BATCH, 1024, 0, stream>>>(coal, actions, w1, b1buf, wfbuf, vbuf,
                                   agent_qs, out);
}

// Round 4
// 156.532 us; speedup vs baseline: 1.3090x; 1.3090x over previous
//
#include <hip/hip_runtime.h>
#include <math.h>

// Shapes: B=32 T=64 N=16 A=20 D=128 S=32 E=64 H=256; batch=2048
// Pipeline:
//  kPack : Wcat=[W1a|Wfa|Wb|Wv1] fp32 (128x640) + bcat; W1b -> Bp bf16 fragment-packed
//  kA2   : X(2048x128) @ Wcat -> h1(bf16), hf(fp32), b1buf, vrelu   (fp32 vector GEMM)
//  kB    : coalition term via permutation bitmasks
//  kC2   : w1 = |h1 @ W1b + b1b|  MFMA bf16 16x16x32, 128x128 tiles -> bf16
//  kSmall: wf = |hf @ Wfb + bfb|  (2048x64, K=256)
//  kD2   : hidden/elu, v, y, w_est, q_tot
// out: q_tot (2048) ++ w_est (2048*16), fp32

#define BATCH 2048

typedef __attribute__((ext_vector_type(8))) short bf16x8;
typedef __attribute__((ext_vector_type(4))) float f32x4;

__device__ inline unsigned short f2bf(float f) {
    unsigned int u = __float_as_uint(f);
    unsigned int r = (u + 0x7FFFu + ((u >> 16) & 1u)) >> 16;
    return (unsigned short)r;
}
__device__ inline float bf2f(unsigned short s) {
    return __uint_as_float(((unsigned int)s) << 16);
}

// ---------------- kPack: weight concat (fp32) + W1b bf16 fragment pack ----------------
__global__ __launch_bounds__(256) void kPack(
    const float* __restrict__ W1a, const float* __restrict__ b1a,
    const float* __restrict__ Wfa, const float* __restrict__ bfa,
    const float* __restrict__ Wb,  const float* __restrict__ bb,
    const float* __restrict__ Wv1, const float* __restrict__ bv1,
    const float* __restrict__ W1b,
    float* __restrict__ Wcat, float* __restrict__ bcat,
    unsigned short* __restrict__ Bp)
{
    const int t = threadIdx.x, bid = blockIdx.x;
    if (bid < 320) {
        int idx = bid * 256 + t;          // 0..81919
        int d = idx / 640, c = idx % 640;
        float v;
        if (c < 256)      v = W1a[d * 256 + c];
        else if (c < 512) v = Wfa[d * 256 + (c - 256)];
        else if (c < 576) v = Wb[d * 64 + (c - 512)];
        else              v = Wv1[d * 64 + (c - 576)];
        Wcat[idx] = v;
        if (idx < 640) {
            int c2 = idx;
            float bv;
            if (c2 < 256)      bv = b1a[c2];
            else if (c2 < 512) bv = bfa[c2 - 256];
            else if (c2 < 576) bv = bb[c2 - 512];
            else               bv = bv1[c2 - 576];
            bcat[c2] = bv;
        }
    } else {
        // Bp[((nb*8+kc)*4+kg)*1024 + n_local*8 + j] = bf16(W1b[(kc*32+kg*8+j)*2560 + nb*128+n_local])
        int idx = (bid - 320) * 256 + t;  // 0..81919
        int n_local = idx & 127;
        int g = idx >> 7;                 // (nb*8+kc)*4+kg
        int kg = g & 3, kcn = g >> 2;
        int kc = kcn & 7, nb = kcn >> 3;
        int kbase = kc * 32 + kg * 8;
        int col = nb * 128 + n_local;
        unsigned short o[8];
        #pragma unroll
        for (int j = 0; j < 8; ++j)
            o[j] = f2bf(W1b[(kbase + j) * 2560 + col]);
        *(uint4*)&Bp[idx * 8] = *(uint4*)o;
    }
}

// ---------------- kA2: X(2048x128) @ Wcat(128x640), fused epilogues ----------------
__global__ __launch_bounds__(256) void kA2(
    const float* __restrict__ X, const float* __restrict__ Wcat,
    const float* __restrict__ bcat,
    unsigned short* __restrict__ h1_bf, float* __restrict__ hf,
    float* __restrict__ b1buf, float* __restrict__ vrelu)
{
    __shared__ float As[16][64];
    __shared__ float Bs[16][64];
    const int tid = threadIdx.x;
    const int tx = tid & 15, ty = tid >> 4;
    const int m0 = blockIdx.y * 64, n0 = blockIdx.x * 64;
    const int lm = tid >> 2, lk = (tid & 3) << 2;
    const int lkk = tid >> 4, lnb = (tid & 15) << 2;

    float c[4][4] = {{0}};
    for (int k0 = 0; k0 < 128; k0 += 16) {
        float4 av = *(const float4*)&X[(m0 + lm) * 128 + k0 + lk];
        As[lk][lm] = av.x; As[lk+1][lm] = av.y; As[lk+2][lm] = av.z; As[lk+3][lm] = av.w;
        *(float4*)&Bs[lkk][lnb] = *(const float4*)&Wcat[(k0 + lkk) * 640 + n0 + lnb];
        __syncthreads();
        #pragma unroll
        for (int kk = 0; kk < 16; ++kk) {
            float4 a4 = *(const float4*)&As[kk][ty * 4];
            float4 b4 = *(const float4*)&Bs[kk][tx * 4];
            float aa[4] = {a4.x, a4.y, a4.z, a4.w};
            float bb4[4] = {b4.x, b4.y, b4.z, b4.w};
            #pragma unroll
            for (int i = 0; i < 4; ++i)
                #pragma unroll
                for (int j = 0; j < 4; ++j)
                    c[i][j] = fmaf(aa[i], bb4[j], c[i][j]);
        }
        __syncthreads();
    }
    const int region = n0 >> 6;      // 0-3 h1, 4-7 hf, 8 b1, 9 vrelu (uniform per block)
    const int n = n0 + tx * 4;
    float4 bias = *(const float4*)&bcat[n];
    #pragma unroll
    for (int i = 0; i < 4; ++i) {
        int m = m0 + ty * 4 + i;
        float v0 = c[i][0] + bias.x, v1 = c[i][1] + bias.y;
        float v2 = c[i][2] + bias.z, v3 = c[i][3] + bias.w;
        if (region < 4) {
            ushort4 o;
            o.x = f2bf(fmaxf(v0, 0.f)); o.y = f2bf(fmaxf(v1, 0.f));
            o.z = f2bf(fmaxf(v2, 0.f)); o.w = f2bf(fmaxf(v3, 0.f));
            *(ushort4*)&h1_bf[m * 256 + n] = o;
        } else if (region < 8) {
            float4 o = { fmaxf(v0,0.f), fmaxf(v1,0.f), fmaxf(v2,0.f), fmaxf(v3,0.f) };
            *(float4*)&hf[m * 256 + (n - 256)] = o;
        } else if (region == 8) {
            float4 o = { v0, v1, v2, v3 };
            *(float4*)&b1buf[m * 64 + (n - 512)] = o;
        } else {
            float4 o = { fmaxf(v0,0.f), fmaxf(v1,0.f), fmaxf(v2,0.f), fmaxf(v3,0.f) };
            *(float4*)&vrelu[m * 64 + (n - 576)] = o;
        }
    }
}

// ---------------- kB: coalition term via permutation bitmasks ----------------
__global__ __launch_bounds__(320) void kB(
    const float* __restrict__ actions, const int* __restrict__ gc,
    float* __restrict__ coal)
{
    __shared__ int aidx[16];
    __shared__ int q[32][16];
    __shared__ unsigned int msk[32][20];
    const int t = threadIdx.x;
    const int b = blockIdx.x;

    for (int idx = t; idx < 512; idx += 320) ((int*)q)[idx] = gc[b * 512 + idx];
    if (t < 16) {
        int a = 0;
        const float* ap = &actions[(b * 16 + t) * 20];
        for (int k = 0; k < 20; ++k) if (ap[k] > 0.5f) a = k;
        aidx[t] = a;
    }
    for (int idx = t; idx < 640; idx += 320) ((unsigned int*)msk)[idx] = 0u;
    __syncthreads();

    if (t < 32) {
        #pragma unroll
        for (int j = 0; j < 16; ++j) {
            int a = aidx[q[t][j]];
            msk[t][a] |= (1u << j);
        }
    }
    __syncthreads();

    const int i = t / 20, a = t % 20;
    float acc = 0.f;
    #pragma unroll 8
    for (int s = 0; s < 32; ++s) {
        int g = q[s][i];
        acc += (float)(g * __popc(msk[s][a] & ((1u << g) - 1u)));
    }
    coal[b * 320 + t] = acc * (1.0f / 512.0f);
}

// ---------------- kC2: w1 = |h1 @ W1b + b1b| via MFMA bf16 ----------------
// A: h1_bf 2048x256 bf16 row-major. B: Bp fragment-packed bf16. C: w1 bf16 2048x2560.
__global__ __launch_bounds__(256) void kC2(
    const unsigned short* __restrict__ A, const unsigned short* __restrict__ Bp,
    const float* __restrict__ bias, unsigned short* __restrict__ C)
{
    __shared__ unsigned short As[128 * 32];   // [row][k] 8KB
    __shared__ unsigned short Bs[4096];       // [kg][n][8] 8KB
    const int t = threadIdx.x;
    const int lane = t & 63, wave = t >> 6;
    const int ln15 = lane & 15, q4 = lane >> 4;      // quad 0..3
    const int m0 = blockIdx.y * 128, nb = blockIdx.x, n0 = nb * 128;
    const int wm = (wave & 1) * 64, wn = (wave >> 1) * 64;

    f32x4 acc[4][4];
    #pragma unroll
    for (int i = 0; i < 4; ++i)
        #pragma unroll
        for (int j = 0; j < 4; ++j)
            acc[i][j] = (f32x4){0.f, 0.f, 0.f, 0.f};

    for (int kc = 0; kc < 8; ++kc) {
        // stage A: 128 rows x 32 bf16 (512 x 16B chunks)
        #pragma unroll
        for (int c = 0; c < 2; ++c) {
            int ch = t + c * 256;
            int row = ch >> 2, part = ch & 3;
            ((uint4*)As)[ch] = *(const uint4*)&A[(m0 + row) * 256 + kc * 32 + part * 8];
        }
        // stage B: contiguous 4096 bf16 chunk
        {
            const uint4* src = (const uint4*)&Bp[(nb * 8 + kc) * 4096];
            ((uint4*)Bs)[t] = src[t];
            ((uint4*)Bs)[t + 256] = src[t + 256];
        }
        __syncthreads();
        bf16x8 af[4], bf[4];
        #pragma unroll
        for (int mi = 0; mi < 4; ++mi)
            af[mi] = *(const bf16x8*)&As[(wm + mi * 16 + ln15) * 32 + q4 * 8];
        #pragma unroll
        for (int ni = 0; ni < 4; ++ni)
            bf[ni] = *(const bf16x8*)&Bs[(q4 * 128 + wn + ni * 16 + ln15) * 8];
        #pragma unroll
        for (int mi = 0; mi < 4; ++mi)
            #pragma unroll
            for (int ni = 0; ni < 4; ++ni)
                acc[mi][ni] = __builtin_amdgcn_mfma_f32_16x16x32_bf16(af[mi], bf[ni], acc[mi][ni], 0, 0, 0);
        __syncthreads();
    }
    #pragma unroll
    for (int ni = 0; ni < 4; ++ni) {
        int col = n0 + wn + ni * 16 + ln15;
        float bv = bias[col];
        #pragma unroll
        for (int mi = 0; mi < 4; ++mi) {
            #pragma unroll
            for (int j = 0; j < 4; ++j) {
                int row = m0 + wm + mi * 16 + q4 * 4 + j;
                C[row * 2560 + col] = f2bf(fabsf(acc[mi][ni][j] + bv));
            }
        }
    }
}

// ---------------- kSmall: wf = |hf @ Wfb + bfb|, M=2048 K=256 N=64 ----------------
__global__ __launch_bounds__(256) void kSmall(
    const float* __restrict__ hf, const float* __restrict__ Wfb,
    const float* __restrict__ bfb, float* __restrict__ wf)
{
    __shared__ float hfs[8][64];
    __shared__ float wfbs[64][64];
    const int t = threadIdx.x;
    const int e = t & 63, mg = t >> 6;
    const int b0 = blockIdx.x * 8;
    float acc0 = 0.f, acc1 = 0.f;

    for (int kc = 0; kc < 4; ++kc) {
        for (int i = t; i < 1024; i += 256)
            ((float4*)wfbs)[i] = ((const float4*)(Wfb + kc * 64 * 64))[i];
        if (t < 128) {
            int r = t >> 4, p = t & 15;
            ((float4*)hfs)[t] = *(const float4*)&hf[(b0 + r) * 256 + kc * 64 + p * 4];
        }
        __syncthreads();
        #pragma unroll 8
        for (int k = 0; k < 64; ++k) {
            float wv = wfbs[k][e];
            acc0 = fmaf(hfs[mg][k], wv, acc0);
            acc1 = fmaf(hfs[mg + 4][k], wv, acc1);
        }
        __syncthreads();
    }
    float bf = bfb[e];
    wf[(b0 + mg) * 64 + e]     = fabsf(acc0 + bf);
    wf[(b0 + mg + 4) * 64 + e] = fabsf(acc1 + bf);
}

// ---------------- kD2: hidden/elu, v, y, w_est, q_tot ----------------
__global__ __launch_bounds__(1024) void kD2(
    const float* __restrict__ coal, const float* __restrict__ actions,
    const unsigned short* __restrict__ w1, const float* __restrict__ b1buf,
    const float* __restrict__ wf, const float* __restrict__ vrelu,
    const float* __restrict__ Wv2, const float* __restrict__ bv2,
    const float* __restrict__ agent_qs, float* __restrict__ out)
{
    __shared__ float ins[16][40];
    __shared__ unsigned short w1s[2560];
    __shared__ float wq[16];
    const int t = threadIdx.x, b = blockIdx.x;

    // disjoint load ranges: [0,320) w1 tile, [320,640) coal, [640,960) actions
    if (t < 320) {
        ((uint4*)w1s)[t] = ((const uint4*)(w1 + b * 2560))[t];
    } else if (t < 640) {
        int u = t - 320;
        ins[u / 20][u % 20] = coal[b * 320 + u];
    } else if (t < 960) {
        int u = t - 640;
        ins[u / 20][20 + u % 20] = actions[b * 320 + u];
    }
    __syncthreads();

    const int i = t >> 6, e = t & 63;
    float acc = b1buf[b * 64 + e];
    #pragma unroll
    for (int k = 0; k < 40; ++k)
        acc = fmaf(ins[i][k], bf2f(w1s[k * 64 + e]), acc);
    float hidden = acc > 0.f ? acc : expm1f(acc);
    float p = hidden * wf[b * 64 + e] + vrelu[b * 64 + e] * Wv2[e];
    #pragma unroll
    for (int off = 32; off > 0; off >>= 1)
        p += __shfl_down(p, off, 64);
    if (e == 0) {
        float west = fabsf(p + bv2[0]);
        out[2048 + b * 16 + i] = west;
        wq[i] = west * agent_qs[b * 16 + i];
    }
    __syncthreads();
    if (t == 0) {
        float s = 0.f;
        #pragma unroll
        for (int ii = 0; ii < 16; ++ii) s += wq[ii];
        out[b] = s;
    }
}

extern "C" void kernel_launch(void* const* d_in, const int* in_sizes, int n_in,
                              void* d_out, int out_size, void* d_ws, size_t ws_size,
                              hipStream_t stream) {
    const float* states   = (const float*)d_in[0];
    const float* actions  = (const float*)d_in[1];
    const float* agent_qs = (const float*)d_in[2];
    const int*   gc       = (const int*)d_in[4];
    const float* W1a = (const float*)d_in[5];
    const float* b1a = (const float*)d_in[6];
    const float* W1b = (const float*)d_in[7];
    const float* b1b = (const float*)d_in[8];
    const float* Wb  = (const float*)d_in[9];
    const float* bb  = (const float*)d_in[10];
    const float* Wfa = (const float*)d_in[11];
    const float* bfa = (const float*)d_in[12];
    const float* Wfb = (const float*)d_in[13];
    const float* bfb = (const float*)d_in[14];
    const float* Wv1 = (const float*)d_in[15];
    const float* bv1 = (const float*)d_in[16];
    const float* Wv2 = (const float*)d_in[17];
    const float* bv2 = (const float*)d_in[18];

    float* ws     = (float*)d_ws;
    float* Wcat   = ws;                      // 81920
    float* bcat   = Wcat + 81920;            // 640
    float* hf     = bcat + 640;              // 524288
    float* b1buf  = hf + 524288;             // 131072
    float* vrelu  = b1buf + 131072;          // 131072
    float* wfbuf  = vrelu + 131072;          // 131072
    float* coal   = wfbuf + 131072;          // 655360
    unsigned short* h1_bf = (unsigned short*)(coal + 655360); // 524288 us
    unsigned short* Bp    = h1_bf + 524288;                   // 655360 us
    unsigned short* w1    = Bp + 655360;                      // 5242880 us
    float* out = (float*)d_out;

    kPack<<<640, 256, 0, stream>>>(W1a, b1a, Wfa, bfa, Wb, bb, Wv1, bv1, W1b,
                                   Wcat, bcat, Bp);
    kB<<<BATCH, 320, 0, stream>>>(actions, gc, coal);
    kA2<<<dim3(10, 32), 256, 0, stream>>>(states, Wcat, bcat, h1_bf, hf, b1buf, vrelu);
    kC2<<<dim3(20, 16), 256, 0, stream>>>(h1_bf, Bp, b1b, w1);
    kSmall<<<256, 256, 0, stream>>>(hf, Wfb, bfb, wfbuf);
    kD2<<<BATCH, 1024, 0, stream>>>(coal, actions, w1, b1buf, wfbuf, vrelu,
                                    Wv2, bv2, agent_qs, out);
}

// Round 5
// 144.874 us; speedup vs baseline: 1.4144x; 1.0805x over previous
//
#include <hip/hip_runtime.h>
#include <math.h>

// Shapes: B=32 T=64 N=16 A=20 D=128 S=32 E=64 H=256; batch=2048
// 3-launch pipeline:
//  k1: blocks 0..319  : X(2048x128) @ [W1a|Wfa|Wb|Wv1] -> h1(bf16), hf, b1buf, vrelu
//      blocks 320..639: W1b -> Bp bf16 fragment-packed
//  k2: blocks 0..319  : w1 = |h1 @ W1b + b1b|  MFMA bf16 128x128 tiles -> bf16
//      blocks 320..575: wf = |hf @ Wfb + bfb|
//  k3: per-batch: coalition bitmasks (in-LDS) + hidden/elu + v + y + w_est + q_tot
// out: q_tot (2048) ++ w_est (2048*16), fp32

#define BATCH 2048

typedef __attribute__((ext_vector_type(8))) short bf16x8;
typedef __attribute__((ext_vector_type(4))) float f32x4;

__device__ inline unsigned short f2bf(float f) {
    unsigned int u = __float_as_uint(f);
    unsigned int r = (u + 0x7FFFu + ((u >> 16) & 1u)) >> 16;
    return (unsigned short)r;
}
__device__ inline float bf2f(unsigned short s) {
    return __uint_as_float(((unsigned int)s) << 16);
}

// ---------------- k1: first-layer GEMM (direct weight reads) + Bp pack ----------------
__global__ __launch_bounds__(256) void k1(
    const float* __restrict__ X,
    const float* __restrict__ W1a, const float* __restrict__ b1a,
    const float* __restrict__ Wfa, const float* __restrict__ bfa,
    const float* __restrict__ Wb,  const float* __restrict__ bb,
    const float* __restrict__ Wv1, const float* __restrict__ bv1,
    const float* __restrict__ W1b,
    unsigned short* __restrict__ h1_bf, float* __restrict__ hf,
    float* __restrict__ b1buf, float* __restrict__ vrelu,
    unsigned short* __restrict__ Bp)
{
    __shared__ float As[16][64];
    __shared__ float Bs[16][64];
    const int t = threadIdx.x, bid = blockIdx.x;

    if (bid >= 320) {
        // Bp[((nb*8+kc)*4+kg)*1024 + n_local*8 + j] = bf16(W1b[(kc*32+kg*8+j)*2560 + nb*128+n_local])
        int idx = (bid - 320) * 256 + t;  // 0..81919
        int n_local = idx & 127;
        int g = idx >> 7;
        int kg = g & 3, kcn = g >> 2;
        int kc = kcn & 7, nb = kcn >> 3;
        int kbase = kc * 32 + kg * 8;
        int col = nb * 128 + n_local;
        unsigned short o[8];
        #pragma unroll
        for (int j = 0; j < 8; ++j)
            o[j] = f2bf(W1b[(kbase + j) * 2560 + col]);
        *(uint4*)&Bp[idx * 8] = *(uint4*)o;
        return;
    }

    const int nb = bid % 10, mb = bid / 10;
    const int m0 = mb * 64, n0 = nb * 64;
    const int tx = t & 15, ty = t >> 4;
    const int lm = t >> 2, lk = (t & 3) << 2;
    const int lkk = t >> 4, lnb = (t & 15) << 2;

    const float* Wsrc; const float* bsrc; int ldb, c0;
    if (nb < 4)       { Wsrc = W1a; bsrc = b1a; ldb = 256; c0 = n0; }
    else if (nb < 8)  { Wsrc = Wfa; bsrc = bfa; ldb = 256; c0 = n0 - 256; }
    else if (nb == 8) { Wsrc = Wb;  bsrc = bb;  ldb = 64;  c0 = 0; }
    else              { Wsrc = Wv1; bsrc = bv1; ldb = 64;  c0 = 0; }

    float c[4][4] = {{0}};
    for (int k0 = 0; k0 < 128; k0 += 16) {
        float4 av = *(const float4*)&X[(m0 + lm) * 128 + k0 + lk];
        As[lk][lm] = av.x; As[lk+1][lm] = av.y; As[lk+2][lm] = av.z; As[lk+3][lm] = av.w;
        *(float4*)&Bs[lkk][lnb] = *(const float4*)&Wsrc[(k0 + lkk) * ldb + c0 + lnb];
        __syncthreads();
        #pragma unroll
        for (int kk = 0; kk < 16; ++kk) {
            float4 a4 = *(const float4*)&As[kk][ty * 4];
            float4 b4 = *(const float4*)&Bs[kk][tx * 4];
            float aa[4] = {a4.x, a4.y, a4.z, a4.w};
            float bb4[4] = {b4.x, b4.y, b4.z, b4.w};
            #pragma unroll
            for (int i = 0; i < 4; ++i)
                #pragma unroll
                for (int j = 0; j < 4; ++j)
                    c[i][j] = fmaf(aa[i], bb4[j], c[i][j]);
        }
        __syncthreads();
    }
    const int ncol = c0 + tx * 4;
    float4 bias = *(const float4*)&bsrc[ncol];
    #pragma unroll
    for (int i = 0; i < 4; ++i) {
        int m = m0 + ty * 4 + i;
        float v0 = c[i][0] + bias.x, v1 = c[i][1] + bias.y;
        float v2 = c[i][2] + bias.z, v3 = c[i][3] + bias.w;
        if (nb < 4) {
            ushort4 o;
            o.x = f2bf(fmaxf(v0, 0.f)); o.y = f2bf(fmaxf(v1, 0.f));
            o.z = f2bf(fmaxf(v2, 0.f)); o.w = f2bf(fmaxf(v3, 0.f));
            *(ushort4*)&h1_bf[m * 256 + ncol] = o;
        } else if (nb < 8) {
            float4 o = { fmaxf(v0,0.f), fmaxf(v1,0.f), fmaxf(v2,0.f), fmaxf(v3,0.f) };
            *(float4*)&hf[m * 256 + ncol] = o;
        } else if (nb == 8) {
            float4 o = { v0, v1, v2, v3 };
            *(float4*)&b1buf[m * 64 + ncol] = o;
        } else {
            float4 o = { fmaxf(v0,0.f), fmaxf(v1,0.f), fmaxf(v2,0.f), fmaxf(v3,0.f) };
            *(float4*)&vrelu[m * 64 + ncol] = o;
        }
    }
}

// ---------------- k2: MFMA GEMM w1 (blocks 0..319) + wf (blocks 320..575) ----------------
__global__ __launch_bounds__(256) void k2(
    const unsigned short* __restrict__ A, const unsigned short* __restrict__ Bp,
    const float* __restrict__ bias, unsigned short* __restrict__ C,
    const float* __restrict__ hf, const float* __restrict__ Wfb,
    const float* __restrict__ bfb, float* __restrict__ wf)
{
    __shared__ __align__(16) char smem[18432];
    const int t = threadIdx.x, bid = blockIdx.x;

    if (bid < 320) {
        unsigned short* As = (unsigned short*)smem;            // 128x32 bf16, 8KB
        unsigned short* Bs = (unsigned short*)(smem + 8192);   // 4096 bf16, 8KB
        const int lane = t & 63, wave = t >> 6;
        const int ln15 = lane & 15, q4 = lane >> 4;
        const int nb = bid % 20, m0 = (bid / 20) * 128, n0 = nb * 128;
        const int wm = (wave & 1) * 64, wn = (wave >> 1) * 64;

        f32x4 acc[4][4];
        #pragma unroll
        for (int i = 0; i < 4; ++i)
            #pragma unroll
            for (int j = 0; j < 4; ++j)
                acc[i][j] = (f32x4){0.f, 0.f, 0.f, 0.f};

        for (int kc = 0; kc < 8; ++kc) {
            #pragma unroll
            for (int c = 0; c < 2; ++c) {
                int ch = t + c * 256;
                int row = ch >> 2, part = ch & 3;
                ((uint4*)As)[ch] = *(const uint4*)&A[(m0 + row) * 256 + kc * 32 + part * 8];
            }
            {
                const uint4* src = (const uint4*)&Bp[(nb * 8 + kc) * 4096];
                ((uint4*)Bs)[t] = src[t];
                ((uint4*)Bs)[t + 256] = src[t + 256];
            }
            __syncthreads();
            bf16x8 af[4], bfr[4];
            #pragma unroll
            for (int mi = 0; mi < 4; ++mi)
                af[mi] = *(const bf16x8*)&As[(wm + mi * 16 + ln15) * 32 + q4 * 8];
            #pragma unroll
            for (int ni = 0; ni < 4; ++ni)
                bfr[ni] = *(const bf16x8*)&Bs[(q4 * 128 + wn + ni * 16 + ln15) * 8];
            #pragma unroll
            for (int mi = 0; mi < 4; ++mi)
                #pragma unroll
                for (int ni = 0; ni < 4; ++ni)
                    acc[mi][ni] = __builtin_amdgcn_mfma_f32_16x16x32_bf16(af[mi], bfr[ni], acc[mi][ni], 0, 0, 0);
            __syncthreads();
        }
        #pragma unroll
        for (int ni = 0; ni < 4; ++ni) {
            int col = n0 + wn + ni * 16 + ln15;
            float bv = bias[col];
            #pragma unroll
            for (int mi = 0; mi < 4; ++mi) {
                #pragma unroll
                for (int j = 0; j < 4; ++j) {
                    int row = m0 + wm + mi * 16 + q4 * 4 + j;
                    C[row * 2560 + col] = f2bf(fabsf(acc[mi][ni][j] + bv));
                }
            }
        }
    } else {
        float* hfs  = (float*)smem;            // [8][64], 2KB
        float* wfbs = (float*)(smem + 2048);   // [64][64], 16KB
        const int e = t & 63, mg = t >> 6;
        const int b0 = (bid - 320) * 8;
        float acc0 = 0.f, acc1 = 0.f;

        for (int kc = 0; kc < 4; ++kc) {
            for (int i = t; i < 1024; i += 256)
                ((float4*)wfbs)[i] = ((const float4*)(Wfb + kc * 64 * 64))[i];
            if (t < 128) {
                int r = t >> 4, p = t & 15;
                ((float4*)hfs)[t] = *(const float4*)&hf[(b0 + r) * 256 + kc * 64 + p * 4];
            }
            __syncthreads();
            #pragma unroll 8
            for (int k = 0; k < 64; ++k) {
                float wv = wfbs[k * 64 + e];
                acc0 = fmaf(hfs[mg * 64 + k], wv, acc0);
                acc1 = fmaf(hfs[(mg + 4) * 64 + k], wv, acc1);
            }
            __syncthreads();
        }
        float bf = bfb[e];
        wf[(b0 + mg) * 64 + e]     = fabsf(acc0 + bf);
        wf[(b0 + mg + 4) * 64 + e] = fabsf(acc1 + bf);
    }
}

// ---------------- k3: coalition (in-LDS) + hidden/elu + v + y + w_est + q_tot ----------------
__global__ __launch_bounds__(1024) void k3(
    const float* __restrict__ actions, const int* __restrict__ gc,
    const unsigned short* __restrict__ w1, const float* __restrict__ b1buf,
    const float* __restrict__ wf, const float* __restrict__ vrelu,
    const float* __restrict__ Wv2, const float* __restrict__ bv2,
    const float* __restrict__ agent_qs, float* __restrict__ out)
{
    __shared__ float ins[16][40];
    __shared__ unsigned short w1s[2560];
    __shared__ int aidx[16];
    __shared__ int q[32][16];
    __shared__ unsigned int msk[32][20];
    __shared__ float wq[16];
    const int t = threadIdx.x, b = blockIdx.x;

    // phase A: parallel loads (disjoint thread ranges)
    if (t < 320) {
        ((uint4*)w1s)[t] = ((const uint4*)(w1 + b * 2560))[t];
    } else if (t < 640) {
        int u = t - 320;                       // 0..319: actions
        float av = actions[b * 320 + u];
        ins[u / 20][20 + u % 20] = av;
        if (av > 0.5f) aidx[u / 20] = u % 20;  // one-hot: exactly one writer per agent
    } else if (t < 768) {
        ((uint4*)q)[t - 640] = ((const uint4*)(gc + b * 512))[t - 640];
    } else if (t < 928) {
        ((uint4*)msk)[t - 768] = make_uint4(0u, 0u, 0u, 0u);
    }
    __syncthreads();

    // phase B: per-sample action position masks (thread s owns msk row s)
    if (t < 32) {
        #pragma unroll
        for (int j = 0; j < 16; ++j)
            msk[t][aidx[q[t][j]]] |= (1u << j);
    }
    __syncthreads();

    // phase C: coal[i][a] directly into ins
    if (t < 320) {
        int i = t / 20, a = t % 20;
        float acc = 0.f;
        #pragma unroll 8
        for (int s = 0; s < 32; ++s) {
            int g = q[s][i];
            acc += (float)(g * __popc(msk[s][a] & ((1u << g) - 1u)));
        }
        ins[i][a] = acc * (1.0f / 512.0f);
    }
    __syncthreads();

    // phase D: hidden/elu + v + y + w_est + q_tot
    const int i = t >> 6, e = t & 63;
    float acc = b1buf[b * 64 + e];
    #pragma unroll
    for (int k = 0; k < 40; ++k)
        acc = fmaf(ins[i][k], bf2f(w1s[k * 64 + e]), acc);
    float hidden = acc > 0.f ? acc : expm1f(acc);
    float p = hidden * wf[b * 64 + e] + vrelu[b * 64 + e] * Wv2[e];
    #pragma unroll
    for (int off = 32; off > 0; off >>= 1)
        p += __shfl_down(p, off, 64);
    if (e == 0) {
        float west = fabsf(p + bv2[0]);
        out[2048 + b * 16 + i] = west;
        wq[i] = west * agent_qs[b * 16 + i];
    }
    __syncthreads();
    if (t == 0) {
        float s = 0.f;
        #pragma unroll
        for (int ii = 0; ii < 16; ++ii) s += wq[ii];
        out[b] = s;
    }
}

extern "C" void kernel_launch(void* const* d_in, const int* in_sizes, int n_in,
                              void* d_out, int out_size, void* d_ws, size_t ws_size,
                              hipStream_t stream) {
    const float* states   = (const float*)d_in[0];
    const float* actions  = (const float*)d_in[1];
    const float* agent_qs = (const float*)d_in[2];
    const int*   gc       = (const int*)d_in[4];
    const float* W1a = (const float*)d_in[5];
    const float* b1a = (const float*)d_in[6];
    const float* W1b = (const float*)d_in[7];
    const float* b1b = (const float*)d_in[8];
    const float* Wb  = (const float*)d_in[9];
    const float* bb  = (const float*)d_in[10];
    const float* Wfa = (const float*)d_in[11];
    const float* bfa = (const float*)d_in[12];
    const float* Wfb = (const float*)d_in[13];
    const float* bfb = (const float*)d_in[14];
    const float* Wv1 = (const float*)d_in[15];
    const float* bv1 = (const float*)d_in[16];
    const float* Wv2 = (const float*)d_in[17];
    const float* bv2 = (const float*)d_in[18];

    float* ws     = (float*)d_ws;
    float* hf     = ws;                      // 524288 f
    float* b1buf  = hf + 524288;             // 131072 f
    float* vrelu  = b1buf + 131072;          // 131072 f
    float* wfbuf  = vrelu + 131072;          // 131072 f
    unsigned short* h1_bf = (unsigned short*)(wfbuf + 131072); // 524288 us
    unsigned short* Bp    = h1_bf + 524288;                    // 655360 us
    unsigned short* w1    = Bp + 655360;                       // 5242880 us
    float* out = (float*)d_out;

    k1<<<640, 256, 0, stream>>>(states, W1a, b1a, Wfa, bfa, Wb, bb, Wv1, bv1,
                                W1b, h1_bf, hf, b1buf, vrelu, Bp);
    k2<<<576, 256, 0, stream>>>(h1_bf, Bp, b1b, w1, hf, Wfb, bfb, wfbuf);
    k3<<<BATCH, 1024, 0, stream>>>(actions, gc, w1, b1buf, wfbuf, vrelu,
                                   Wv2, bv2, agent_qs, out);
}

// Round 7
// 137.031 us; speedup vs baseline: 1.4953x; 1.0572x over previous
//
#include <hip/hip_runtime.h>
#include <math.h>

// Shapes: B=32 T=64 N=16 A=20 D=128 S=32 E=64 H=256; batch=2048
// 3-launch pipeline:
//  k1: blocks 0..319  : X(2048x128) @ [W1a|Wfa|Wb|Wv1] -> h1(bf16), hf, b1buf, vrelu
//      blocks 320..639: W1b -> Bp bf16 fragment-packed
//  k2: blocks 0..319  : w1 = |h1 @ W1b + b1b|  MFMA bf16 128x128 tiles -> bf16
//      blocks 320..575: wf = |hf @ Wfb + bfb|
//  k3: per-batch: coalition bitmasks (in-LDS) + hidden/elu (one-hot action row) + q_tot
// out: q_tot (2048) ++ w_est (2048*16), fp32

#define BATCH 2048

typedef __attribute__((ext_vector_type(8))) short bf16x8;
typedef __attribute__((ext_vector_type(4))) float f32x4;

__device__ inline unsigned short f2bf(float f) {
    unsigned int u = __float_as_uint(f);
    unsigned int r = (u + 0x7FFFu + ((u >> 16) & 1u)) >> 16;
    return (unsigned short)r;
}
__device__ inline float bf2f(unsigned short s) {
    return __uint_as_float(((unsigned int)s) << 16);
}

// ---------------- k1: first-layer GEMM (direct weight reads) + Bp pack ----------------
__global__ __launch_bounds__(256) void k1(
    const float* __restrict__ X,
    const float* __restrict__ W1a, const float* __restrict__ b1a,
    const float* __restrict__ Wfa, const float* __restrict__ bfa,
    const float* __restrict__ Wb,  const float* __restrict__ bb,
    const float* __restrict__ Wv1, const float* __restrict__ bv1,
    const float* __restrict__ W1b,
    unsigned short* __restrict__ h1_bf, float* __restrict__ hf,
    float* __restrict__ b1buf, float* __restrict__ vrelu,
    unsigned short* __restrict__ Bp)
{
    __shared__ float As[16][64];
    __shared__ float Bs[16][64];
    const int t = threadIdx.x, bid = blockIdx.x;

    if (bid >= 320) {
        // Bp[((nb*8+kc)*4+kg)*1024 + n_local*8 + j] = bf16(W1b[(kc*32+kg*8+j)*2560 + nb*128+n_local])
        int idx = (bid - 320) * 256 + t;  // 0..81919
        int n_local = idx & 127;
        int g = idx >> 7;
        int kg = g & 3, kcn = g >> 2;
        int kc = kcn & 7, nb = kcn >> 3;
        int kbase = kc * 32 + kg * 8;
        int col = nb * 128 + n_local;
        unsigned short o[8];
        #pragma unroll
        for (int j = 0; j < 8; ++j)
            o[j] = f2bf(W1b[(kbase + j) * 2560 + col]);
        *(uint4*)&Bp[idx * 8] = *(uint4*)o;
        return;
    }

    const int nb = bid % 10, mb = bid / 10;
    const int m0 = mb * 64, n0 = nb * 64;
    const int tx = t & 15, ty = t >> 4;
    const int lm = t >> 2, lk = (t & 3) << 2;
    const int lkk = t >> 4, lnb = (t & 15) << 2;

    const float* Wsrc; const float* bsrc; int ldb, c0;
    if (nb < 4)       { Wsrc = W1a; bsrc = b1a; ldb = 256; c0 = n0; }
    else if (nb < 8)  { Wsrc = Wfa; bsrc = bfa; ldb = 256; c0 = n0 - 256; }
    else if (nb == 8) { Wsrc = Wb;  bsrc = bb;  ldb = 64;  c0 = 0; }
    else              { Wsrc = Wv1; bsrc = bv1; ldb = 64;  c0 = 0; }

    float c[4][4] = {{0}};
    for (int k0 = 0; k0 < 128; k0 += 16) {
        float4 av = *(const float4*)&X[(m0 + lm) * 128 + k0 + lk];
        As[lk][lm] = av.x; As[lk+1][lm] = av.y; As[lk+2][lm] = av.z; As[lk+3][lm] = av.w;
        *(float4*)&Bs[lkk][lnb] = *(const float4*)&Wsrc[(k0 + lkk) * ldb + c0 + lnb];
        __syncthreads();
        #pragma unroll
        for (int kk = 0; kk < 16; ++kk) {
            float4 a4 = *(const float4*)&As[kk][ty * 4];
            float4 b4 = *(const float4*)&Bs[kk][tx * 4];
            float aa[4] = {a4.x, a4.y, a4.z, a4.w};
            float bb4[4] = {b4.x, b4.y, b4.z, b4.w};
            #pragma unroll
            for (int i = 0; i < 4; ++i)
                #pragma unroll
                for (int j = 0; j < 4; ++j)
                    c[i][j] = fmaf(aa[i], bb4[j], c[i][j]);
        }
        __syncthreads();
    }
    const int ncol = c0 + tx * 4;
    float4 bias = *(const float4*)&bsrc[ncol];
    #pragma unroll
    for (int i = 0; i < 4; ++i) {
        int m = m0 + ty * 4 + i;
        float v0 = c[i][0] + bias.x, v1 = c[i][1] + bias.y;
        float v2 = c[i][2] + bias.z, v3 = c[i][3] + bias.w;
        if (nb < 4) {
            ushort4 o;
            o.x = f2bf(fmaxf(v0, 0.f)); o.y = f2bf(fmaxf(v1, 0.f));
            o.z = f2bf(fmaxf(v2, 0.f)); o.w = f2bf(fmaxf(v3, 0.f));
            *(ushort4*)&h1_bf[m * 256 + ncol] = o;
        } else if (nb < 8) {
            float4 o = { fmaxf(v0,0.f), fmaxf(v1,0.f), fmaxf(v2,0.f), fmaxf(v3,0.f) };
            *(float4*)&hf[m * 256 + ncol] = o;
        } else if (nb == 8) {
            float4 o = { v0, v1, v2, v3 };
            *(float4*)&b1buf[m * 64 + ncol] = o;
        } else {
            float4 o = { fmaxf(v0,0.f), fmaxf(v1,0.f), fmaxf(v2,0.f), fmaxf(v3,0.f) };
            *(float4*)&vrelu[m * 64 + ncol] = o;
        }
    }
}

// ---------------- k2: MFMA GEMM w1 (blocks 0..319) + wf (blocks 320..575) ----------------
// As rows padded to 40 shorts (80B) to spread fragment reads across all 32 banks.
#define AS_STRIDE 40
__global__ __launch_bounds__(256) void k2(
    const unsigned short* __restrict__ A, const unsigned short* __restrict__ Bp,
    const float* __restrict__ bias, unsigned short* __restrict__ C,
    const float* __restrict__ hf, const float* __restrict__ Wfb,
    const float* __restrict__ bfb, float* __restrict__ wf)
{
    __shared__ __align__(16) char smem[18432];
    const int t = threadIdx.x, bid = blockIdx.x;

    if (bid < 320) {
        unsigned short* As = (unsigned short*)smem;            // 128 x 40 bf16, 10240B
        unsigned short* Bs = (unsigned short*)(smem + 10240);  // 4096 bf16, 8192B
        const int lane = t & 63, wave = t >> 6;
        const int ln15 = lane & 15, q4 = lane >> 4;
        const int nb = bid % 20, m0 = (bid / 20) * 128, n0 = nb * 128;
        const int wm = (wave & 1) * 64, wn = (wave >> 1) * 64;

        f32x4 acc[4][4];
        #pragma unroll
        for (int i = 0; i < 4; ++i)
            #pragma unroll
            for (int j = 0; j < 4; ++j)
                acc[i][j] = (f32x4){0.f, 0.f, 0.f, 0.f};

        for (int kc = 0; kc < 8; ++kc) {
            #pragma unroll
            for (int c = 0; c < 2; ++c) {
                int ch = t + c * 256;
                int row = ch >> 2, part = ch & 3;
                *(uint4*)&As[row * AS_STRIDE + part * 8] =
                    *(const uint4*)&A[(m0 + row) * 256 + kc * 32 + part * 8];
            }
            {
                const uint4* src = (const uint4*)&Bp[(nb * 8 + kc) * 4096];
                ((uint4*)Bs)[t] = src[t];
                ((uint4*)Bs)[t + 256] = src[t + 256];
            }
            __syncthreads();
            bf16x8 af[4], bfr[4];
            #pragma unroll
            for (int mi = 0; mi < 4; ++mi)
                af[mi] = *(const bf16x8*)&As[(wm + mi * 16 + ln15) * AS_STRIDE + q4 * 8];
            #pragma unroll
            for (int ni = 0; ni < 4; ++ni)
                bfr[ni] = *(const bf16x8*)&Bs[(q4 * 128 + wn + ni * 16 + ln15) * 8];
            #pragma unroll
            for (int mi = 0; mi < 4; ++mi)
                #pragma unroll
                for (int ni = 0; ni < 4; ++ni)
                    acc[mi][ni] = __builtin_amdgcn_mfma_f32_16x16x32_bf16(af[mi], bfr[ni], acc[mi][ni], 0, 0, 0);
            __syncthreads();
        }
        #pragma unroll
        for (int ni = 0; ni < 4; ++ni) {
            int col = n0 + wn + ni * 16 + ln15;
            float bv = bias[col];
            #pragma unroll
            for (int mi = 0; mi < 4; ++mi) {
                #pragma unroll
                for (int j = 0; j < 4; ++j) {
                    int row = m0 + wm + mi * 16 + q4 * 4 + j;
                    C[row * 2560 + col] = f2bf(fabsf(acc[mi][ni][j] + bv));
                }
            }
        }
    } else {
        float* hfs  = (float*)smem;            // [8][64], 2KB
        float* wfbs = (float*)(smem + 2048);   // [64][64], 16KB
        const int e = t & 63, mg = t >> 6;
        const int b0 = (bid - 320) * 8;
        float acc0 = 0.f, acc1 = 0.f;

        for (int kc = 0; kc < 4; ++kc) {
            for (int i = t; i < 1024; i += 256)
                ((float4*)wfbs)[i] = ((const float4*)(Wfb + kc * 64 * 64))[i];
            if (t < 128) {
                int r = t >> 4, p = t & 15;
                ((float4*)hfs)[t] = *(const float4*)&hf[(b0 + r) * 256 + kc * 64 + p * 4];
            }
            __syncthreads();
            #pragma unroll 8
            for (int k = 0; k < 64; ++k) {
                float wv = wfbs[k * 64 + e];
                acc0 = fmaf(hfs[mg * 64 + k], wv, acc0);
                acc1 = fmaf(hfs[(mg + 4) * 64 + k], wv, acc1);
            }
            __syncthreads();
        }
        float bf = bfb[e];
        wf[(b0 + mg) * 64 + e]     = fabsf(acc0 + bf);
        wf[(b0 + mg + 4) * 64 + e] = fabsf(acc1 + bf);
    }
}

// ---------------- k3: coalition (in-LDS) + hidden/elu (one-hot row) + q_tot ----------------
__global__ __launch_bounds__(1024) void k3(
    const float* __restrict__ actions, const int* __restrict__ gc,
    const unsigned short* __restrict__ w1, const float* __restrict__ b1buf,
    const float* __restrict__ wf, const float* __restrict__ vrelu,
    const float* __restrict__ Wv2, const float* __restrict__ bv2,
    const float* __restrict__ agent_qs, float* __restrict__ out)
{
    __shared__ float ins[16][20];             // coal only (action half is one-hot)
    __shared__ unsigned short w1s[1280];      // w1 rows 0..19
    __shared__ int aidx[16];
    __shared__ int q[32][16];
    __shared__ unsigned int msk[32][20];
    __shared__ float wq[16];
    const int t = threadIdx.x, b = blockIdx.x;

    // phase A: parallel loads (disjoint thread ranges)
    if (t < 160) {
        ((uint4*)w1s)[t] = ((const uint4*)(w1 + b * 2560))[t];   // rows 0..19
    } else if (t < 480) {
        int u = t - 160;                      // 0..319: actions -> aidx (one-hot argmax)
        float av = actions[b * 320 + u];
        if (av > 0.5f) aidx[u / 20] = u % 20; // exactly one writer per agent
    } else if (t < 608) {
        ((uint4*)q)[t - 480] = ((const uint4*)(gc + b * 512))[t - 480];
    } else if (t < 768) {
        ((uint4*)msk)[t - 608] = make_uint4(0u, 0u, 0u, 0u);   // 160 x 16B = 640 uints
    }
    __syncthreads();

    // phase B: per-sample action position masks, 512 threads, one atomicOr each
    if (t >= 512) {
        int u = t - 512, s = u >> 4, j = u & 15;
        atomicOr(&msk[s][aidx[q[s][j]]], 1u << j);
    }
    __syncthreads();

    // phase C: coal[i][a] into ins
    if (t < 320) {
        int i = t / 20, a = t % 20;
        float acc = 0.f;
        #pragma unroll 8
        for (int s = 0; s < 32; ++s) {
            int g = q[s][i];
            acc += (float)(g * __popc(msk[s][a] & ((1u << g) - 1u)));
        }
        ins[i][a] = acc * (1.0f / 512.0f);
    }
    __syncthreads();

    // phase D: hidden/elu + v + y + w_est + q_tot
    const int i = t >> 6, e = t & 63;
    float acc = b1buf[b * 64 + e];
    #pragma unroll
    for (int k = 0; k < 20; ++k)
        acc = fmaf(ins[i][k], bf2f(w1s[k * 64 + e]), acc);
    acc += bf2f(w1[b * 2560 + (20 + aidx[i]) * 64 + e]);  // one-hot action row
    float hidden = acc > 0.f ? acc : expm1f(acc);
    float p = hidden * wf[b * 64 + e] + vrelu[b * 64 + e] * Wv2[e];
    #pragma unroll
    for (int off = 32; off > 0; off >>= 1)
        p += __shfl_down(p, off, 64);
    if (e == 0) {
        float west = fabsf(p + bv2[0]);
        out[2048 + b * 16 + i] = west;
        wq[i] = west * agent_qs[b * 16 + i];
    }
    __syncthreads();
    if (t == 0) {
        float s = 0.f;
        #pragma unroll
        for (int ii = 0; ii < 16; ++ii) s += wq[ii];
        out[b] = s;
    }
}

extern "C" void kernel_launch(void* const* d_in, const int* in_sizes, int n_in,
                              void* d_out, int out_size, void* d_ws, size_t ws_size,
                              hipStream_t stream) {
    const float* states   = (const float*)d_in[0];
    const float* actions  = (const float*)d_in[1];
    const float* agent_qs = (const float*)d_in[2];
    const int*   gc       = (const int*)d_in[4];
    const float* W1a = (const float*)d_in[5];
    const float* b1a = (const float*)d_in[6];
    const float* W1b = (const float*)d_in[7];
    const float* b1b = (const float*)d_in[8];
    const float* Wb  = (const float*)d_in[9];
    const float* bb  = (const float*)d_in[10];
    const float* Wfa = (const float*)d_in[11];
    const float* bfa = (const float*)d_in[12];
    const float* Wfb = (const float*)d_in[13];
    const float* bfb = (const float*)d_in[14];
    const float* Wv1 = (const float*)d_in[15];
    const float* bv1 = (const float*)d_in[16];
    const float* Wv2 = (const float*)d_in[17];
    const float* bv2 = (const float*)d_in[18];

    float* ws     = (float*)d_ws;
    float* hf     = ws;                      // 524288 f
    float* b1buf  = hf + 524288;             // 131072 f
    float* vrelu  = b1buf + 131072;          // 131072 f
    float* wfbuf  = vrelu + 131072;          // 131072 f
    unsigned short* h1_bf = (unsigned short*)(wfbuf + 131072); // 524288 us
    unsigned short* Bp    = h1_bf + 524288;                    // 655360 us
    unsigned short* w1    = Bp + 655360;                       // 5242880 us
    float* out = (float*)d_out;

    k1<<<640, 256, 0, stream>>>(states, W1a, b1a, Wfa, bfa, Wb, bb, Wv1, bv1,
                                W1b, h1_bf, hf, b1buf, vrelu, Bp);
    k2<<<576, 256, 0, stream>>>(h1_bf, Bp, b1b, w1, hf, Wfb, bfb, wfbuf);
    k3<<<BATCH, 1024, 0, stream>>>(actions, gc, w1, b1buf, wfbuf, vrelu,
                                   Wv2, bv2, agent_qs, out);
}